// Round 1
// baseline (550.669 us; speedup 1.0000x reference)
//
#include <hip/hip_runtime.h>

// Problem constants (from reference):
// x: [16, 3, 64, 64, 64] f32; weight: [16, 3, 3, 3, 3] f32; conv valid -> 62^3
// out: mean over spatial of GroupNorm(hardswish(conv+bias)) -> [16,16] f32
constexpr int CIN = 3, DIMSZ = 64, COUT = 16, OD = 62;
constexpr int NSP = OD * OD * OD;          // 238328 spatial outputs
constexpr float EPSV = 1e-5f;

// Fused conv3d + bias + hardswish + per-channel/per-group partial sums.
// grid = 16 (b) * 62 (d') * 2 (h-half) = 1984 blocks, 256 threads.
// Each thread (tid<248): one (h', w-segment-of-8) row piece, all 16 channels.
__global__ __launch_bounds__(256, 2)
void conv_gn_fused(const float* __restrict__ x, const float* __restrict__ wgt,
                   const float* __restrict__ cbias,
                   float* __restrict__ S1, float* __restrict__ S2)
{
    __shared__ float wlds[81 * 16];   // [k=ci*27+kd*9+kh*3+kw][co]
    __shared__ float blds[16];
    const int tid = threadIdx.x;
    for (int i = tid; i < 81 * 16; i += 256) {
        int k = i >> 4, co = i & 15;
        wlds[i] = wgt[co * 81 + k];   // transpose OIDHW -> [k][co]
    }
    if (tid < 16) blds[tid] = cbias[tid];
    __syncthreads();

    const int blk  = blockIdx.x;      // 0..1983
    const int b    = blk / 124;
    const int rem  = blk % 124;
    const int dp   = rem >> 1;        // output depth index 0..61
    const int half = rem & 1;         // h half: rows [half*31, half*31+31)

    float s1[16];
    float s2g[4];
#pragma unroll
    for (int i = 0; i < 16; ++i) s1[i] = 0.f;
#pragma unroll
    for (int i = 0; i < 4; ++i)  s2g[i] = 0.f;

    if (tid < 248) {                  // 31 h-rows * 8 w-segments
        const int hp = half * 31 + (tid >> 3);   // output h 0..61
        const int w0 = (tid & 7) << 3;           // 0,8,...,56
        const float* xb = x + (size_t)b * (CIN * DIMSZ * DIMSZ * DIMSZ);

        float acc[16][8];
#pragma unroll
        for (int co = 0; co < 16; ++co)
#pragma unroll
            for (int wb = 0; wb < 8; ++wb) acc[co][wb] = 0.f;

#pragma unroll
        for (int ci = 0; ci < 3; ++ci) {
#pragma unroll
            for (int kd = 0; kd < 3; ++kd) {
#pragma unroll
                for (int kh = 0; kh < 3; ++kh) {
                    const float* xp = xb + ((ci * DIMSZ + dp + kd) * DIMSZ + hp + kh) * DIMSZ;
                    float in[10];
                    const float4 v0 = *reinterpret_cast<const float4*>(xp + w0);
                    const float4 v1 = *reinterpret_cast<const float4*>(xp + w0 + 4);
                    in[0] = v0.x; in[1] = v0.y; in[2] = v0.z; in[3] = v0.w;
                    in[4] = v1.x; in[5] = v1.y; in[6] = v1.z; in[7] = v1.w;
                    // w0+8 / w0+9 overflow the row only when w0==56; clamped
                    // values feed only discarded (invalid) outputs.
                    int w8 = w0 + 8; if (w8 > 63) w8 = 63;
                    int w9 = w0 + 9; if (w9 > 63) w9 = 63;
                    in[8] = xp[w8]; in[9] = xp[w9];
                    const float* wp = &wlds[(ci * 9 + kd * 3 + kh) * 48];
#pragma unroll
                    for (int kw = 0; kw < 3; ++kw) {
#pragma unroll
                        for (int co = 0; co < 16; ++co) {
                            const float wv = wp[kw * 16 + co];  // uniform LDS broadcast
#pragma unroll
                            for (int wb = 0; wb < 8; ++wb)
                                acc[co][wb] = fmaf(wv, in[wb + kw], acc[co][wb]);
                        }
                    }
                }
            }
        }

        // bias + hardswish + partial sums (mask w >= 62)
        const int nvalid = (w0 == 56) ? 6 : 8;
#pragma unroll
        for (int co = 0; co < 16; ++co) {
            const float bz = blds[co];
            float ls1 = 0.f, ls2 = 0.f;
#pragma unroll
            for (int wb = 0; wb < 8; ++wb) {
                const float z = acc[co][wb] + bz;
                const float r = fminf(fmaxf(z + 3.0f, 0.0f), 6.0f);
                const float a = z * r * (1.0f / 6.0f);
                const bool ok = wb < nvalid;
                ls1 += ok ? a : 0.f;
                ls2 += ok ? a * a : 0.f;
            }
            s1[co] += ls1;
            s2g[co >> 2] += ls2;
        }
    }

    // 64-lane butterfly reduction of 20 partials, then per-wave atomics.
#pragma unroll
    for (int off = 32; off > 0; off >>= 1) {
#pragma unroll
        for (int i = 0; i < 16; ++i) s1[i] += __shfl_down(s1[i], off);
#pragma unroll
        for (int i = 0; i < 4; ++i)  s2g[i] += __shfl_down(s2g[i], off);
    }
    if ((tid & 63) == 0) {
#pragma unroll
        for (int i = 0; i < 16; ++i) atomicAdd(&S1[b * 16 + i], s1[i]);
#pragma unroll
        for (int i = 0; i < 4; ++i)  atomicAdd(&S2[b * 4 + i], s2g[i]);
    }
}

// out[b,c] = gw[c]*(S1[b,c]/N - mu[b,g])*rsqrt(var+eps) + gb[c]
__global__ void gn_finalize(const float* __restrict__ S1, const float* __restrict__ S2,
                            const float* __restrict__ gw, const float* __restrict__ gb,
                            float* __restrict__ out)
{
    const int t = threadIdx.x;        // 0..255
    const int b = t >> 4, c = t & 15, g = c >> 2;
    const float invGN = 1.0f / (4.0f * (float)NSP);
    const float sumg = S1[b * 16 + g * 4 + 0] + S1[b * 16 + g * 4 + 1] +
                       S1[b * 16 + g * 4 + 2] + S1[b * 16 + g * 4 + 3];
    const float mu   = sumg * invGN;
    const float var  = S2[b * 4 + g] * invGN - mu * mu;
    const float meanc = S1[b * 16 + c] * (1.0f / (float)NSP);
    out[t] = gw[c] * (meanc - mu) * rsqrtf(var + EPSV) + gb[c];
}

extern "C" void kernel_launch(void* const* d_in, const int* in_sizes, int n_in,
                              void* d_out, int out_size, void* d_ws, size_t ws_size,
                              hipStream_t stream) {
    const float* x  = (const float*)d_in[0];
    const float* w  = (const float*)d_in[1];
    const float* cb = (const float*)d_in[2];
    const float* gw = (const float*)d_in[3];
    const float* gb = (const float*)d_in[4];
    float* out = (float*)d_out;

    float* S1 = (float*)d_ws;         // 16*16 floats
    float* S2 = S1 + 256;             // 16*4 floats
    hipMemsetAsync(d_ws, 0, (256 + 64) * sizeof(float), stream);

    conv_gn_fused<<<16 * 62 * 2, 256, 0, stream>>>(x, w, cb, S1, S2);
    gn_finalize<<<1, 256, 0, stream>>>(S1, S2, gw, gb, out);
}

// Round 3
// 201.602 us; speedup vs baseline: 2.7315x; 2.7315x over previous
//
#include <hip/hip_runtime.h>

// x: [16, 3, 64, 64, 64] f32; weight: [16, 3, 3, 3, 3] f32; conv valid -> 62^3
// out[b,c] = gw[c]*(mean_sp(a) - mu[b,g])*rsqrt(var[b,g]+eps) + gb[c],
// a = hardswish(conv+bias). Only per-channel sums S1 and per-group sums-of-
// squares S2 are needed -> fused conv + reduction, never materialize a.
constexpr int OD = 62;
constexpr int NSP = OD * OD * OD;          // 238328
constexpr float EPSV = 1e-5f;

// ws layout (floats): S1[256] | S2[64] | w2[81*16]
// w2[k][co] = weight[co][k]  (k = ci*27 + kd*9 + kh*3 + kw, contiguous co)

__global__ void prep_weights(const float* __restrict__ wgt, float* __restrict__ w2)
{
    for (int i = threadIdx.x; i < 81 * 16; i += 256) {
        const int k = i >> 4, co = i & 15;
        w2[i] = wgt[co * 81 + k];
    }
}

// grid = 16 (b) * 62 (dp) * 4 (row-quarter) = 3968 blocks, 256 threads.
// thread: row = quarter*16 + (tid>>4)  (valid if <62), w-seg of 4 = (tid&15)*4.
// acc[16 cout][4 w] = 64 VGPRs -> no spill (round-1 had 128-float acc with
// VGPR_Count=120 => spilled => VALUBusy 17.5%).
__global__ __launch_bounds__(256, 4)
void conv_gn_fused(const float* __restrict__ x, const float* __restrict__ w2,
                   const float* __restrict__ cbias,
                   float* __restrict__ S1, float* __restrict__ S2)
{
    const int tid = threadIdx.x;
    __shared__ float red[20];
    if (tid < 20) red[tid] = 0.f;
    __syncthreads();

    const int blk     = blockIdx.x;        // 0..3967
    const int b       = blk / 248;
    const int rem     = blk % 248;
    const int dp      = rem >> 2;          // 0..61
    const int quarter = rem & 3;

    const int  row  = quarter * 16 + (tid >> 4);   // 0..63
    const bool vrow = row < OD;
    const int  hp   = vrow ? row : (OD - 1);       // clamp keeps loads in-bounds
    const int  w0   = (tid & 15) << 2;             // 0,4,...,60
    const int  nv   = (w0 + 4 <= OD) ? 4 : (OD - w0);   // 4, except seg15 -> 2
    const float* xb = x + (size_t)b * (3 * 64 * 64 * 64);

    float acc[16][4];
#pragma unroll
    for (int co = 0; co < 16; ++co)
#pragma unroll
        for (int wb = 0; wb < 4; ++wb) acc[co][wb] = 0.f;

#pragma unroll
    for (int ci = 0; ci < 3; ++ci) {
#pragma unroll
        for (int kd = 0; kd < 3; ++kd) {
#pragma unroll
            for (int kh = 0; kh < 3; ++kh) {
                const float* xp = xb + ((ci * 64 + dp + kd) * 64 + hp + kh) * 64;
                float in[6];
                const float4 v0 = *reinterpret_cast<const float4*>(xp + w0);
                // w0+4..w0+5: for seg15 (w0=60) that crosses the row end; those
                // values only feed masked-out outputs, so clamp the address to
                // stay in-bounds (values are garbage-but-finite).
                const int w4 = (w0 == 60) ? 56 : (w0 + 4);
                const float2 v1 = *reinterpret_cast<const float2*>(xp + w4);
                in[0] = v0.x; in[1] = v0.y; in[2] = v0.z; in[3] = v0.w;
                in[4] = v1.x; in[5] = v1.y;

                // uniform, contiguous -> scalar (s_load) weight reads
                const float* wp = w2 + (ci * 9 + kd * 3 + kh) * 48;
#pragma unroll
                for (int kw = 0; kw < 3; ++kw) {
#pragma unroll
                    for (int co = 0; co < 16; ++co) {
                        const float wv = wp[kw * 16 + co];
#pragma unroll
                        for (int wb = 0; wb < 4; ++wb)
                            acc[co][wb] = fmaf(wv, in[wb + kw], acc[co][wb]);
                    }
                }
            }
        }
    }

    // bias + hardswish + masked partial sums
    float s1[16], s2g[4];
#pragma unroll
    for (int i = 0; i < 4; ++i) s2g[i] = 0.f;
#pragma unroll
    for (int co = 0; co < 16; ++co) {
        const float bz = cbias[co];            // uniform scalar load
        float ls1 = 0.f, ls2 = 0.f;
#pragma unroll
        for (int wb = 0; wb < 4; ++wb) {
            const float z = acc[co][wb] + bz;
            const float r = fminf(fmaxf(z + 3.0f, 0.0f), 6.0f);
            const float a = z * r * (1.0f / 6.0f);
            const bool ok = vrow && (wb < nv);
            ls1 += ok ? a : 0.f;
            ls2 += ok ? a * a : 0.f;
        }
        s1[co] = ls1;
        s2g[co >> 2] += ls2;
    }

    // 64-lane butterfly, then LDS-combine across the 4 waves, then 20 global
    // atomics per block (248 blocks/address -> negligible contention).
#pragma unroll
    for (int off = 32; off > 0; off >>= 1) {
#pragma unroll
        for (int i = 0; i < 16; ++i) s1[i] += __shfl_down(s1[i], off);
#pragma unroll
        for (int i = 0; i < 4; ++i)  s2g[i] += __shfl_down(s2g[i], off);
    }
    if ((tid & 63) == 0) {
#pragma unroll
        for (int i = 0; i < 16; ++i) atomicAdd(&red[i], s1[i]);
#pragma unroll
        for (int i = 0; i < 4; ++i)  atomicAdd(&red[16 + i], s2g[i]);
    }
    __syncthreads();
    if (tid < 16)      atomicAdd(&S1[b * 16 + tid], red[tid]);
    else if (tid < 20) atomicAdd(&S2[b * 4 + (tid - 16)], red[tid]);
}

// out[b,c] = gw[c]*(S1[b,c]/N - mu[b,g])*rsqrt(var+eps) + gb[c]
__global__ void gn_finalize(const float* __restrict__ S1, const float* __restrict__ S2,
                            const float* __restrict__ gw, const float* __restrict__ gb,
                            float* __restrict__ out)
{
    const int t = threadIdx.x;        // 0..255
    const int b = t >> 4, c = t & 15, g = c >> 2;
    const float invGN = 1.0f / (4.0f * (float)NSP);
    const float sumg = S1[b * 16 + g * 4 + 0] + S1[b * 16 + g * 4 + 1] +
                       S1[b * 16 + g * 4 + 2] + S1[b * 16 + g * 4 + 3];
    const float mu    = sumg * invGN;
    const float var   = S2[b * 4 + g] * invGN - mu * mu;
    const float meanc = S1[b * 16 + c] * (1.0f / (float)NSP);
    out[t] = gw[c] * (meanc - mu) * rsqrtf(var + EPSV) + gb[c];
}

extern "C" void kernel_launch(void* const* d_in, const int* in_sizes, int n_in,
                              void* d_out, int out_size, void* d_ws, size_t ws_size,
                              hipStream_t stream) {
    const float* x  = (const float*)d_in[0];
    const float* w  = (const float*)d_in[1];
    const float* cb = (const float*)d_in[2];
    const float* gw = (const float*)d_in[3];
    const float* gb = (const float*)d_in[4];
    float* out = (float*)d_out;

    float* S1 = (float*)d_ws;          // 256 floats
    float* S2 = S1 + 256;              // 64 floats
    float* w2 = S2 + 64;               // 81*16 floats
    hipMemsetAsync(d_ws, 0, (256 + 64) * sizeof(float), stream);

    prep_weights<<<1, 256, 0, stream>>>(w, w2);
    conv_gn_fused<<<16 * 62 * 4, 256, 0, stream>>>(x, w2, cb, S1, S2);
    gn_finalize<<<1, 256, 0, stream>>>(S1, S2, gw, gb, out);
}

// Round 7
// 192.104 us; speedup vs baseline: 2.8665x; 1.0494x over previous
//
#include <hip/hip_runtime.h>
#include <stdint.h>

// x: [16,3,64,64,64] f32; w: [16,3,3,3,3] f32; conv valid -> 62^3.
// out[b,c] = gw[c]*(mean_sp(a)-mu[b,g])*rsqrt(var[b,g]+eps)+gb[c],
// a = hardswish(conv+bias) -> only per-channel sums S1 / per-group sum-sq S2
// are needed. Conv done as implicit GEMM on bf16 MFMA:
//   per output row (b,dp,hp): M=16 w-positions x N=16 cout, K=27 (ci,kd,kh)
//   padded to 32; kw realized as 3 column-shifted reads of one im2col array.
// Weights split hi+lo bf16 (removes correlated rounding bias); x single bf16
// (zero-mean rounding averages out over the 238328-elem spatial mean).
constexpr int OD = 62;
constexpr float EPSV = 1e-5f;

typedef __attribute__((ext_vector_type(8))) short bf16x8;  // 8 bf16 = 4 VGPR
typedef __attribute__((ext_vector_type(4))) float f32x4;

__device__ __forceinline__ uint32_t bf16rne(float f) {
    uint32_t u = __float_as_uint(f);
    return (u + 0x7FFFu + ((u >> 16) & 1u)) >> 16;
}
__device__ __forceinline__ float bf16tof(uint32_t h) { return __uint_as_float(h << 16); }

union U8 { uint32_t u[4]; bf16x8 v; };

// grid = 16(b) * 62(dp) * 16(hp-group) blocks of 256; wave q -> row hp=hpg*4+q.
__global__ __launch_bounds__(256, 4)
void conv_mfma(const float* __restrict__ x, const float* __restrict__ wgt,
               const float* __restrict__ cbias, float* __restrict__ part)
{
    // im2col per wave: 4 g-chunks x 66 columns x 4 pair-dwords (16B/column):
    // dword (wq*4+g)*264 + c*4 + p4 holds bf16 pair (k'=8g+2*p4, 8g+2*p4+1)
    // of column c. A-frag(lane) = ds_read_b128 at column c = t*16+lm+kw.
    __shared__ __align__(16) uint32_t im2[4224];
    __shared__ float red[20];
    const int tid = threadIdx.x, wq = tid >> 6, l = tid & 63;
    const int lm = l & 15, lg = l >> 4;
    if (tid < 20) red[tid] = 0.f;
    __syncthreads();

    const int bid = blockIdx.x;
    const int b   = bid / 992;
    const int r   = bid % 992;
    const int dp  = r >> 4;            // 0..61
    const int hp  = (r & 15) * 4 + wq; // 0..63 (>=62 -> idle wave)

    if (hp < OD) {
        // ---- B fragments: lane holds W[co=lm][k'=8*lg+j][kw], hi+lo bf16 ----
        bf16x8 Bhi[3], Blo[3];
#pragma unroll
        for (int kw = 0; kw < 3; ++kw) {
            U8 hi, lo;
#pragma unroll
            for (int p = 0; p < 4; ++p) {
                uint32_t h01[2], l01[2];
#pragma unroll
                for (int e = 0; e < 2; ++e) {
                    const int kp = lg * 8 + p * 2 + e;
                    float wv = (kp < 27) ? wgt[lm * 81 + kp * 3 + kw] : 0.f;
                    const uint32_t h = bf16rne(wv);
                    h01[e] = h;
                    l01[e] = bf16rne(wv - bf16tof(h));
                }
                hi.u[p] = h01[0] | (h01[1] << 16);
                lo.u[p] = l01[0] | (l01[1] << 16);
            }
            Bhi[kw] = hi.v; Blo[kw] = lo.v;
        }

        // ---- build im2col: lane l = column c = w index 0..63 ----
        const float* base2 = x + (size_t)b * 786432 + dp * 4096 + hp * 64 + l;
#pragma unroll
        for (int g = 0; g < 4; ++g) {
            float v[8];
#pragma unroll
            for (int jj = 0; jj < 8; ++jj) {
                const int kp = g * 8 + jj;            // k' = ci*9+kd*3+kh
                if (kp < 27) {
                    const int ci = kp / 9, kd = (kp % 9) / 3, kh = kp % 3;
                    v[jj] = base2[ci * 262144 + kd * 4096 + kh * 64];
                } else v[jj] = 0.f;
            }
            const uint32_t d0 = bf16rne(v[0]) | (bf16rne(v[1]) << 16);
            const uint32_t d1 = bf16rne(v[2]) | (bf16rne(v[3]) << 16);
            const uint32_t d2 = bf16rne(v[4]) | (bf16rne(v[5]) << 16);
            const uint32_t d3 = bf16rne(v[6]) | (bf16rne(v[7]) << 16);
            *reinterpret_cast<uint4*>(&im2[(wq * 4 + g) * 264 + l * 4]) =
                make_uint4(d0, d1, d2, d3);
            if (l < 2)  // zero pad columns 64,65 (read by shifted tiles; keep finite)
                *reinterpret_cast<uint4*>(&im2[(wq * 4 + g) * 264 + (64 + l) * 4]) =
                    make_uint4(0u, 0u, 0u, 0u);
        }
        // wave-private LDS region: compiler orders ds_write->ds_read via lgkmcnt;
        // no cross-wave sharing, so no barrier needed here.

        // ---- MFMA: 4 M-tiles x 3 kw-shifts x (hi,lo) into 4 accumulators ----
        f32x4 acc[4] = {{0,0,0,0},{0,0,0,0},{0,0,0,0},{0,0,0,0}};
        const uint32_t* abase = &im2[wq * 1056 + lg * 264];
#pragma unroll
        for (int t = 0; t < 4; ++t) {
#pragma unroll
            for (int kw = 0; kw < 3; ++kw) {
                const bf16x8 a =
                    *reinterpret_cast<const bf16x8*>(abase + (t * 16 + lm + kw) * 4);
                acc[t] = __builtin_amdgcn_mfma_f32_16x16x32_bf16(a, Bhi[kw], acc[t], 0, 0, 0);
                acc[t] = __builtin_amdgcn_mfma_f32_16x16x32_bf16(a, Blo[kw], acc[t], 0, 0, 0);
            }
        }

        // ---- epilogue: bias+hardswish+masked sums; C: col=lane&15,row=lg*4+reg ----
        const float bz = cbias[lm];
        float s1 = 0.f, s2 = 0.f;
#pragma unroll
        for (int t = 0; t < 4; ++t) {
#pragma unroll
            for (int rr = 0; rr < 4; ++rr) {
                const int m = lg * 4 + rr;
                const float z = acc[t][rr] + bz;
                const float r6 = fminf(fmaxf(z + 3.f, 0.f), 6.f);
                const float a = z * r6 * (1.f / 6.f);
                if (t < 3) { s1 += a; s2 += a * a; }
                else { const bool ok = m < 14;       // w = 48+m < 62
                       s1 += ok ? a : 0.f; s2 += ok ? a * a : 0.f; }
            }
        }
        // combine lanes sharing co (l, l^16, l^32, ...), then co-group for s2
        s1 += __shfl_xor(s1, 16); s1 += __shfl_xor(s1, 32);
        s2 += __shfl_xor(s2, 16); s2 += __shfl_xor(s2, 32);
        float s2g = s2;
        s2g += __shfl_xor(s2g, 1); s2g += __shfl_xor(s2g, 2);
        if (l < 16) {
            atomicAdd(&red[l], s1);
            if ((l & 3) == 0) atomicAdd(&red[16 + (l >> 2)], s2g);
        }
    }
    __syncthreads();
    if (tid < 20) part[bid * 20 + tid] = red[tid];   // pure writes: no ws memset
}

// One block per batch: reduce 992 partial rows of 20, emit out[b][0..15].
__global__ void gn_finalize(const float* __restrict__ part, const float* __restrict__ gw,
                            const float* __restrict__ gb, float* __restrict__ out)
{
    __shared__ float ac[12][20];
    const int t = threadIdx.x, b = blockIdx.x;
    if (t < 240) {
        const int s = t % 20, r0 = t / 20;
        float a = 0.f;
        for (int j = r0; j < 992; j += 12) a += part[(b * 992 + j) * 20 + s];
        ac[r0][s] = a;
    }
    __syncthreads();
    if (t < 20) {
        float a = 0.f;
#pragma unroll
        for (int q = 0; q < 12; ++q) a += ac[q][t];
        ac[0][t] = a;           // thread t touches only column t: no hazard
    }
    __syncthreads();
    if (t < 16) {
        const float invN  = 1.0f / 238328.0f;
        const float invGN = 1.0f / (4.0f * 238328.0f);
        const int g = t >> 2;
        const float mu  = (ac[0][g * 4] + ac[0][g * 4 + 1] +
                           ac[0][g * 4 + 2] + ac[0][g * 4 + 3]) * invGN;
        const float var = ac[0][16 + g] * invGN - mu * mu;
        out[b * 16 + t] = gw[t] * (ac[0][t] * invN - mu) * rsqrtf(var + EPSV) + gb[t];
    }
}

extern "C" void kernel_launch(void* const* d_in, const int* in_sizes, int n_in,
                              void* d_out, int out_size, void* d_ws, size_t ws_size,
                              hipStream_t stream) {
    const float* x  = (const float*)d_in[0];
    const float* w  = (const float*)d_in[1];
    const float* cb = (const float*)d_in[2];
    const float* gw = (const float*)d_in[3];
    const float* gb = (const float*)d_in[4];
    float* out  = (float*)d_out;
    float* part = (float*)d_ws;                     // 15872*20 f32 = 1.27 MB

    conv_mfma<<<16 * 62 * 16, 256, 0, stream>>>(x, w, cb, part);
    gn_finalize<<<16, 256, 0, stream>>>(part, gw, gb, out);
}

// Round 11
// 127.970 us; speedup vs baseline: 4.3031x; 1.5012x over previous
//
#include <hip/hip_runtime.h>
#include <stdint.h>

// x: [16,3,64,64,64] f32; w: [16,3,3,3,3] f32; conv valid -> 62^3.
// out[b,c] = gw[c]*(mean_sp(a)-mu[b,g])*rsqrt(var[b,g]+eps)+gb[c],
// a = hardswish(conv+bias) -> only per-channel sums S1 / per-group sum-sq S2
// needed. Conv = implicit GEMM on bf16 MFMA (per row: M=16 w x N=16 cout,
// K=27->32; kw as 3 column-shifted reads of one per-wave im2col).
// R7 evidence: VALUBusy 54 / MfmaUtil 9.4 -> VALU-bound on per-wave weight
// re-conversion + manual bf16 packing; finalize latency-serial (~87us gap).
// R8: B-frags precomputed to ws (prep kernel), v_cvt_pk_bf16_f32 for im2col,
// part[] relaid [b][s][block] for a coalesced wave-per-segment finalize.
constexpr int OD = 62;
constexpr float EPSV = 1e-5f;
constexpr int NBLK = 992;                  // conv blocks per batch (62 dp * 16)
constexpr int PSTRIDE = 20 * NBLK;         // floats per batch in part[]

typedef __attribute__((ext_vector_type(8))) short bf16x8;  // 8 bf16 = 4 VGPR
typedef __attribute__((ext_vector_type(4))) float f32x4;

__device__ __forceinline__ uint32_t bf16rne(float f) {
    uint32_t u = __float_as_uint(f);
    return (u + 0x7FFFu + ((u >> 16) & 1u)) >> 16;
}
__device__ __forceinline__ float bf16tof(uint32_t h) { return __uint_as_float(h << 16); }
__device__ __forceinline__ uint32_t cvtpk(float a, float b) {   // lo=bf16(a), hi=bf16(b), RNE
    uint32_t r;
    asm("v_cvt_pk_bf16_f32 %0, %1, %2" : "=v"(r) : "v"(a), "v"(b));
    return r;
}

union U8 { uint32_t u[4]; bf16x8 v; };

// Precompute per-lane B-fragment dword images: Bw[(kw*2+sel)*64 + l] =
// 4 dwords, dword p = pack(W[lm][lg*8+2p][kw], W[lm][lg*8+2p+1][kw]) hi/lo-split.
__global__ void prep_bfrag(const float* __restrict__ wgt, uint4* __restrict__ Bw)
{
    const int i = threadIdx.x;             // 384 threads: (kw,sel,l)
    if (i < 384) {
        const int kw = i >> 7, sel = (i >> 6) & 1, l = i & 63;
        const int lm = l & 15, lg = l >> 4;
        uint32_t d[4];
#pragma unroll
        for (int p = 0; p < 4; ++p) {
            uint32_t pk[2];
#pragma unroll
            for (int e = 0; e < 2; ++e) {
                const int kp = lg * 8 + p * 2 + e;
                const float wv = (kp < 27) ? wgt[lm * 81 + kp * 3 + kw] : 0.f;
                const uint32_t h = bf16rne(wv);
                pk[e] = sel ? bf16rne(wv - bf16tof(h)) : h;
            }
            d[p] = pk[0] | (pk[1] << 16);
        }
        Bw[i] = make_uint4(d[0], d[1], d[2], d[3]);
    }
}

// grid = 16(b) * 62(dp) * 16(hp-group) blocks of 256; wave q -> row hp=hpg*4+q.
__global__ __launch_bounds__(256, 4)
void conv_mfma(const float* __restrict__ x, const uint4* __restrict__ Bw,
               const float* __restrict__ cbias, float* __restrict__ part)
{
    // im2col per wave: 4 g-chunks x 66 columns x 4 pair-dwords (16B/column).
    __shared__ __align__(16) uint32_t im2[4224];
    __shared__ float red[20];
    const int tid = threadIdx.x, wq = tid >> 6, l = tid & 63;
    const int lm = l & 15, lg = l >> 4;
    if (tid < 20) red[tid] = 0.f;
    __syncthreads();

    const int bid = blockIdx.x;
    const int b   = bid / NBLK;
    const int r   = bid % NBLK;
    const int dp  = r >> 4;            // 0..61
    const int hp  = (r & 15) * 4 + wq; // 0..63 (>=62 -> idle wave)

    if (hp < OD) {
        // ---- B fragments: precomputed per-lane dwords, 6x dwordx4 loads ----
        bf16x8 Bhi[3], Blo[3];
#pragma unroll
        for (int kw = 0; kw < 3; ++kw) {
            U8 h, lo;
            *reinterpret_cast<uint4*>(h.u)  = Bw[(kw * 2 + 0) * 64 + l];
            *reinterpret_cast<uint4*>(lo.u) = Bw[(kw * 2 + 1) * 64 + l];
            Bhi[kw] = h.v; Blo[kw] = lo.v;
        }

        // ---- build im2col: lane l = column c = w index 0..63 ----
        const float* base2 = x + (size_t)b * 786432 + dp * 4096 + hp * 64 + l;
#pragma unroll
        for (int g = 0; g < 4; ++g) {
            float v[8];
#pragma unroll
            for (int jj = 0; jj < 8; ++jj) {
                const int kp = g * 8 + jj;            // k' = ci*9+kd*3+kh
                if (kp < 27) {
                    const int ci = kp / 9, kd = (kp % 9) / 3, kh = kp % 3;
                    v[jj] = base2[ci * 262144 + kd * 4096 + kh * 64];
                } else v[jj] = 0.f;
            }
            const uint32_t d0 = cvtpk(v[0], v[1]);
            const uint32_t d1 = cvtpk(v[2], v[3]);
            const uint32_t d2 = cvtpk(v[4], v[5]);
            const uint32_t d3 = cvtpk(v[6], v[7]);
            *reinterpret_cast<uint4*>(&im2[(wq * 4 + g) * 264 + l * 4]) =
                make_uint4(d0, d1, d2, d3);
            if (l < 2)  // zero pad columns 64,65 (read by shifted tiles)
                *reinterpret_cast<uint4*>(&im2[(wq * 4 + g) * 264 + (64 + l) * 4]) =
                    make_uint4(0u, 0u, 0u, 0u);
        }
        // wave-private LDS region: same-wave ds_write->ds_read ordered by lgkmcnt.

        // ---- MFMA: 4 M-tiles x 3 kw-shifts x (hi,lo) ----
        f32x4 acc[4] = {{0,0,0,0},{0,0,0,0},{0,0,0,0},{0,0,0,0}};
        const uint32_t* abase = &im2[wq * 1056 + lg * 264];
#pragma unroll
        for (int t = 0; t < 4; ++t) {
#pragma unroll
            for (int kw = 0; kw < 3; ++kw) {
                const bf16x8 a =
                    *reinterpret_cast<const bf16x8*>(abase + (t * 16 + lm + kw) * 4);
                acc[t] = __builtin_amdgcn_mfma_f32_16x16x32_bf16(a, Bhi[kw], acc[t], 0, 0, 0);
                acc[t] = __builtin_amdgcn_mfma_f32_16x16x32_bf16(a, Blo[kw], acc[t], 0, 0, 0);
            }
        }

        // ---- epilogue: bias+hardswish+masked sums; C: col=lane&15,row=lg*4+reg ----
        const float bz = cbias[lm];
        float s1 = 0.f, s2 = 0.f;
#pragma unroll
        for (int t = 0; t < 4; ++t) {
#pragma unroll
            for (int rr = 0; rr < 4; ++rr) {
                const int m = lg * 4 + rr;
                const float z = acc[t][rr] + bz;
                const float r6 = fminf(fmaxf(z + 3.f, 0.f), 6.f);
                const float a = z * r6 * (1.f / 6.f);
                if (t < 3) { s1 += a; s2 += a * a; }
                else { const bool ok = m < 14;       // w = 48+m < 62
                       s1 += ok ? a : 0.f; s2 += ok ? a * a : 0.f; }
            }
        }
        s1 += __shfl_xor(s1, 16); s1 += __shfl_xor(s1, 32);
        s2 += __shfl_xor(s2, 16); s2 += __shfl_xor(s2, 32);
        float s2g = s2;
        s2g += __shfl_xor(s2g, 1); s2g += __shfl_xor(s2g, 2);
        if (l < 16) {
            atomicAdd(&red[l], s1);
            if ((l & 3) == 0) atomicAdd(&red[16 + (l >> 2)], s2g);
        }
    }
    __syncthreads();
    // part[b][s][r]: finalize reads each segment s as 992 contiguous floats.
    if (tid < 20) part[b * PSTRIDE + tid * NBLK + r] = red[tid];
}

// 16 blocks (one per b) x 4 waves; wave reduces 5 segments of 992 floats
// with masked float4 loads + 64-lane shuffle reduce. ~5us total.
__global__ __launch_bounds__(256)
void gn_finalize(const float* __restrict__ part, const float* __restrict__ gw,
                 const float* __restrict__ gb, float* __restrict__ out)
{
    __shared__ float tot[20];
    const int t = threadIdx.x, b = blockIdx.x;
    const int wq = t >> 6, l = t & 63;
#pragma unroll
    for (int i = 0; i < 5; ++i) {
        const int s = wq * 5 + i;
        const float4* base = reinterpret_cast<const float4*>(part + b * PSTRIDE + s * NBLK);
        float a = 0.f;
#pragma unroll
        for (int j = 0; j < 4; ++j) {
            const int idx = j * 64 + l;          // 992 floats = 248 float4
            if (idx < 248) { const float4 v = base[idx]; a += (v.x + v.y) + (v.z + v.w); }
        }
#pragma unroll
        for (int off = 32; off > 0; off >>= 1) a += __shfl_down(a, off);
        if (l == 0) tot[s] = a;
    }
    __syncthreads();
    if (t < 16) {
        const float invN  = 1.0f / 238328.0f;
        const float invGN = 1.0f / (4.0f * 238328.0f);
        const int g = t >> 2;
        const float mu  = (tot[g * 4] + tot[g * 4 + 1] +
                           tot[g * 4 + 2] + tot[g * 4 + 3]) * invGN;
        const float var = tot[16 + g] * invGN - mu * mu;
        out[b * 16 + t] = gw[t] * (tot[t] * invN - mu) * rsqrtf(var + EPSV) + gb[t];
    }
}

extern "C" void kernel_launch(void* const* d_in, const int* in_sizes, int n_in,
                              void* d_out, int out_size, void* d_ws, size_t ws_size,
                              hipStream_t stream) {
    const float* x  = (const float*)d_in[0];
    const float* w  = (const float*)d_in[1];
    const float* cb = (const float*)d_in[2];
    const float* gw = (const float*)d_in[3];
    const float* gb = (const float*)d_in[4];
    float* out  = (float*)d_out;
    float* part = (float*)d_ws;                       // 16*20*992 f32 = 1.27 MB
    uint4* Bw   = (uint4*)(part + 16 * PSTRIDE);      // 384 uint4 = 6 KB

    prep_bfrag<<<1, 384, 0, stream>>>(w, Bw);
    conv_mfma<<<16 * 62 * 16, 256, 0, stream>>>(x, Bw, cb, part);
    gn_finalize<<<16, 256, 0, stream>>>(part, gw, gb, out);
}